// Round 2
// baseline (244.032 us; speedup 1.0000x reference)
//
#include <hip/hip_runtime.h>

// LightweightConv1d: y[b,t,c] = sum_k softmax(w)[c%H,k] * x[b, t+k-PAD, c]
// x: (B,T,C) fp32 contiguous (C innermost), w: (H,1,K) fp32, y: (B,T,C) fp32.
// Compulsory traffic 268 MB -> ~43 us at 6.3 TB/s.
// R2 post-mortem: bench dur 232 us = ~161 us harness poison-fills (2x80.5, seen in
//   rocprof top-5) + conv ~71 us. Conv was 369 MB (1.75x read amp) at ~82% eff.
// R3: TCHUNK=16 (amp 1.375x) + XCD-aware remap (halo rows -> same-XCD L2 hits;
//   default round-robin put adjacent t-chunks on different XCDs) + nontemporal
//   y-stores (y has zero reuse; stop evicting x from L2/L3).
// R4: fix compile — __builtin_nontemporal_store needs a NATIVE vector type,
//   not HIP_vector_type<float,4>; store through ext_vector_type(4) float*.

constexpr int B_   = 8;
constexpr int T_   = 4096;
constexpr int C_   = 1024;
constexpr int H_   = 16;
constexpr int K_   = 7;
constexpr int PAD_ = 3;
constexpr int TCHUNK = 16;            // outputs per thread along T
constexpr int W_  = TCHUNK + K_ - 1;  // 22 input rows per chunk
constexpr int C4  = C_ / 4;           // 256 float4 per row == blockDim.x
constexpr int NCHUNK = T_ / TCHUNK;   // 256 chunks per batch image
constexpr int NXCD = 8;

typedef float vfloat4 __attribute__((ext_vector_type(4)));  // native, nt-storable

// win[22] = 88 VGPR + wr 28 + misc ~15 -> ~130 VGPR: needs the 168-cap of
// min-3-waves/SIMD (12 waves/CU; 12x22KB = 264KB reads in flight per CU,
// ~25x the ~10 B/cyc/CU HBM share -> latency still fully hidden).
__global__ __launch_bounds__(256, 3) void lwconv_kernel(
    const float* __restrict__ x, const float* __restrict__ w,
    float* __restrict__ y) {
  __shared__ float ws[H_][K_];
  const int tid = threadIdx.x;

  // Per-head softmax over K (112 values; threads 0..15 each do one head).
  if (tid < H_) {
    float v[K_];
    float m = -1e30f;
#pragma unroll
    for (int k = 0; k < K_; ++k) { v[k] = w[tid * K_ + k]; m = fmaxf(m, v[k]); }
    float s = 0.f;
#pragma unroll
    for (int k = 0; k < K_; ++k) { v[k] = expf(v[k] - m); s += v[k]; }
    const float inv = 1.f / s;
#pragma unroll
    for (int k = 0; k < K_; ++k) ws[tid][k] = v[k] * inv;
  }
  __syncthreads();

  // Thread handles 4 consecutive channels c = 4*tid .. 4*tid+3.
  const int h0 = (4 * tid) & (H_ - 1);
  float wr[4][K_];
#pragma unroll
  for (int j = 0; j < 4; ++j)
#pragma unroll
    for (int k = 0; k < K_; ++k) wr[j][k] = ws[h0 + j][k];

  // XCD-aware remap: hw round-robins consecutive blockIdx across the 8 XCDs.
  // Remap so XCD i owns work-ids [i*256, (i+1)*256) = ALL 256 t-chunks of
  // batch image b=i (grid 2048 = 8*256, bijective). Adjacent chunks (sharing
  // the 6-row/24KB halo) then run on the same XCD close in time -> L2 hits.
  const int cpx = (B_ * NCHUNK) / NXCD;   // 256
  const int wid = ((int)blockIdx.x % NXCD) * cpx + (int)blockIdx.x / NXCD;
  const int b  = wid / NCHUNK;
  const int t0 = (wid % NCHUNK) * TCHUNK;

  const float4* __restrict__ xr =
      reinterpret_cast<const float4*>(x + (size_t)b * T_ * C_) + tid;
  vfloat4* __restrict__ yr =
      reinterpret_cast<vfloat4*>(y + (size_t)b * T_ * C_) + tid;

  const float4 z4 = make_float4(0.f, 0.f, 0.f, 0.f);

  // Batch-load all W_=22 input rows (22 KB/wave in flight).
  float4 win[W_];
#pragma unroll
  for (int i = 0; i < W_; ++i) {
    const int t = t0 - PAD_ + i;  // wave-uniform predicate -> scalar branch
    win[i] = (t >= 0 && t < T_) ? xr[(size_t)t * C4] : z4;
  }

#pragma unroll
  for (int tt = 0; tt < TCHUNK; ++tt) {
    float ax = 0.f, ay = 0.f, az = 0.f, aw = 0.f;
#pragma unroll
    for (int k = 0; k < K_; ++k) {
      ax = fmaf(win[tt + k].x, wr[0][k], ax);
      ay = fmaf(win[tt + k].y, wr[1][k], ay);
      az = fmaf(win[tt + k].z, wr[2][k], az);
      aw = fmaf(win[tt + k].w, wr[3][k], aw);
    }
    // y is written once, never read: nontemporal keeps x resident in L2/L3.
    vfloat4 out;
    out.x = ax; out.y = ay; out.z = az; out.w = aw;
    __builtin_nontemporal_store(out, yr + (size_t)(t0 + tt) * C4);
  }
}

extern "C" void kernel_launch(void* const* d_in, const int* in_sizes, int n_in,
                              void* d_out, int out_size, void* d_ws, size_t ws_size,
                              hipStream_t stream) {
  const float* x = (const float*)d_in[0];   // (B,T,C) fp32
  const float* w = (const float*)d_in[1];   // (H,1,K) fp32
  float* y = (float*)d_out;                 // (B,T,C) fp32

  const int grid = B_ * NCHUNK;             // 2048 blocks
  lwconv_kernel<<<grid, 256, 0, stream>>>(x, w, y);
}

// Round 3
// 236.623 us; speedup vs baseline: 1.0313x; 1.0313x over previous
//
#include <hip/hip_runtime.h>

// LightweightConv1d: y[b,t,c] = sum_k softmax(w)[c%H,k] * x[b, t+k-PAD, c]
// x: (B,T,C) fp32 contiguous (C innermost), w: (H,1,K) fp32, y: (B,T,C) fp32.
// Compulsory traffic 268 MB -> ~43 us at 6.3 TB/s.
// R4 post-mortem (conv measured directly for the first time): 92.5 us,
//   hbm 2.2 TB/s (28%), VALUBusy 7%, Occupancy 28% -> LATENCY-bound, not BW.
//   Causes: VGPR=68 (>64 -> waves/CU halves to 16) and grid=2048 (8 blk/CU).
//   Also: FETCH=70MB < x's 134MB -> L3 retains x across iters and absorbs the
//   halo re-reads; read amplification is nearly free, VGPR/parallelism is not.
// R5: reverse the trade. E=2 channels/thread (float2), TCHUNK=8 (W=14):
//   win 14x2=28 VGPR + weights 14 -> ~52 total, forced <=64 via
//   __launch_bounds__(256,8) -> 32 waves/CU. Grid 8192 (=32 blk/CU).
//   Keep XCD remap (t-adjacent halo -> same-XCD L2) + nt stores (protect x L3).

constexpr int B_   = 8;
constexpr int T_   = 4096;
constexpr int C_   = 1024;
constexpr int H_   = 16;
constexpr int K_   = 7;
constexpr int PAD_ = 3;
constexpr int TCHUNK = 8;             // outputs per thread along T
constexpr int W_  = TCHUNK + K_ - 1;  // 14 input rows per chunk
constexpr int NCHUNK = T_ / TCHUNK;   // 512 chunks per batch image
constexpr int CSPLIT = 2;             // C split across blocks: 512 ch per block
constexpr int CH  = C_ / CSPLIT;      // 512 channels per block
constexpr int C2  = C_ / 2;           // float2 per full row = 512
constexpr int NXCD = 8;

typedef float vfloat2 __attribute__((ext_vector_type(2)));  // native, nt-storable

// ~52 VGPR needed; (256,8) caps at 64 -> 8 waves/SIMD = 32 waves/CU.
__global__ __launch_bounds__(256, 8) void lwconv_kernel(
    const float* __restrict__ x, const float* __restrict__ w,
    float* __restrict__ y) {
  __shared__ float ws[H_][K_];
  const int tid = threadIdx.x;

  // Per-head softmax over K (112 values; threads 0..15 each do one head).
  if (tid < H_) {
    float v[K_];
    float m = -1e30f;
#pragma unroll
    for (int k = 0; k < K_; ++k) { v[k] = w[tid * K_ + k]; m = fmaxf(m, v[k]); }
    float s = 0.f;
#pragma unroll
    for (int k = 0; k < K_; ++k) { v[k] = expf(v[k] - m); s += v[k]; }
    const float inv = 1.f / s;
#pragma unroll
    for (int k = 0; k < K_; ++k) ws[tid][k] = v[k] * inv;
  }
  __syncthreads();

  // XCD-aware remap: hw round-robins consecutive blockIdx across 8 XCDs.
  // wid layout: wid = pair*NCHUNK + tc, pair = chalf*B + b. Each XCD owns a
  // contiguous 1024-wid range (2 full image-halves); consecutive wids are
  // t-adjacent chunks -> 6-row halo (12 KB) hits that XCD's L2.
  const int cpx = (B_ * CSPLIT * NCHUNK) / NXCD;   // 1024
  const int wid = ((int)blockIdx.x % NXCD) * cpx + (int)blockIdx.x / NXCD;
  const int pair  = wid / NCHUNK;          // 0..15
  const int tc    = wid % NCHUNK;
  const int b     = pair & (B_ - 1);
  const int chalf = pair >> 3;             // 0 or 1
  const int t0    = tc * TCHUNK;

  // Thread handles 2 consecutive channels c = chalf*512 + 2*tid (+0,+1).
  // 512 % 16 == 0 so head index is independent of chalf.
  const int h0 = (2 * tid) & (H_ - 1);
  float wr[2][K_];
#pragma unroll
  for (int j = 0; j < 2; ++j)
#pragma unroll
    for (int k = 0; k < K_; ++k) wr[j][k] = ws[h0 + j][k];

  const float2* __restrict__ xr =
      reinterpret_cast<const float2*>(x + (size_t)b * T_ * C_ + chalf * CH) + tid;
  vfloat2* __restrict__ yr =
      reinterpret_cast<vfloat2*>(y + (size_t)b * T_ * C_ + chalf * CH) + tid;

  const float2 z2 = make_float2(0.f, 0.f);

  // Batch-load all W_=14 input rows (14 independent loads, 7 KB/wave in flight;
  // 32 waves/CU -> ~224 KB/CU outstanding during the load phase).
  float2 win[W_];
#pragma unroll
  for (int i = 0; i < W_; ++i) {
    const int t = t0 - PAD_ + i;  // wave-uniform predicate -> scalar branch
    win[i] = (t >= 0 && t < T_) ? xr[(size_t)t * C2] : z2;
  }

#pragma unroll
  for (int tt = 0; tt < TCHUNK; ++tt) {
    float ax = 0.f, ay = 0.f;
#pragma unroll
    for (int k = 0; k < K_; ++k) {
      ax = fmaf(win[tt + k].x, wr[0][k], ax);
      ay = fmaf(win[tt + k].y, wr[1][k], ay);
    }
    // y is written once, never read: nontemporal keeps x resident in L2/L3.
    vfloat2 out;
    out.x = ax; out.y = ay;
    __builtin_nontemporal_store(out, yr + (size_t)(t0 + tt) * C2);
  }
}

extern "C" void kernel_launch(void* const* d_in, const int* in_sizes, int n_in,
                              void* d_out, int out_size, void* d_ws, size_t ws_size,
                              hipStream_t stream) {
  const float* x = (const float*)d_in[0];   // (B,T,C) fp32
  const float* w = (const float*)d_in[1];   // (H,1,K) fp32
  float* y = (float*)d_out;                 // (B,T,C) fp32

  const int grid = B_ * CSPLIT * NCHUNK;    // 8192 blocks
  lwconv_kernel<<<grid, 256, 0, stream>>>(x, w, y);
}